// Round 1
// baseline (6919.746 us; speedup 1.0000x reference)
//
#include <hip/hip_runtime.h>
#include <hip/hip_bf16.h>

#define M_ROWS 65536
#define N_COLS 8192
#define K_DIM  1024
#define CAP    32
#define MARGIN 2.5f

typedef __attribute__((ext_vector_type(8))) short bf16x8;
typedef __attribute__((ext_vector_type(4))) float f32x4;

__device__ __forceinline__ unsigned short f32_to_bf16_rne(float f) {
  unsigned int u = __float_as_uint(f);
  unsigned int r = u + 0x7fffu + ((u >> 16) & 1u);
  return (unsigned short)(r >> 16);
}

// ---- kernel: zero the per-row candidate counts (ws is poisoned 0xAA) ----
__global__ void vq_init(int* __restrict__ counts) {
  int i = blockIdx.x * blockDim.x + threadIdx.x;
  if (i < M_ROWS) counts[i] = 0;
}

// ---- kernel: convert z (fp32) -> bf16, vectorized ----
__global__ void vq_convert_z(const float* __restrict__ z, unsigned short* __restrict__ zb) {
  int i = blockIdx.x * blockDim.x + threadIdx.x;  // float4 index
  float4 v = ((const float4*)z)[i];
  ushort4 o;
  o.x = f32_to_bf16_rne(v.x);
  o.y = f32_to_bf16_rne(v.y);
  o.z = f32_to_bf16_rne(v.z);
  o.w = f32_to_bf16_rne(v.w);
  ((ushort4*)zb)[i] = o;
}

// ---- kernel: transpose codebook [K][N] -> cbT [N][K] in fp32 and bf16 ----
__global__ void vq_transpose_cb(const float* __restrict__ cb,
                                float* __restrict__ cbT,
                                unsigned short* __restrict__ cbTb) {
  __shared__ float tile[32][33];
  int n0 = blockIdx.x * 32;
  int k0 = blockIdx.y * 32;
  int tx = threadIdx.x;  // 0..31
  int ty = threadIdx.y;  // 0..7
#pragma unroll
  for (int i = 0; i < 4; ++i) {
    int k = k0 + ty + i * 8;
    tile[ty + i * 8][tx] = cb[(size_t)k * N_COLS + n0 + tx];
  }
  __syncthreads();
#pragma unroll
  for (int i = 0; i < 4; ++i) {
    int n = n0 + ty + i * 8;
    float v = tile[tx][ty + i * 8];
    cbT[(size_t)n * K_DIM + k0 + tx] = v;
    cbTb[(size_t)n * K_DIM + k0 + tx] = f32_to_bf16_rne(v);
  }
}

// ---- main kernel: bf16 MFMA GEMM fused with per-row running-min + candidate record ----
// grid = M/128 blocks; each block owns a 128-row stripe and loops over all 64 column
// chunks of 128. Each of 4 waves owns 32 rows x 128 cols (2 m-subtiles x 8 n-subtiles).
__global__ __launch_bounds__(256) void vq_gemm(const unsigned short* __restrict__ zb,
                                               const unsigned short* __restrict__ cbTb,
                                               int* __restrict__ counts,
                                               int* __restrict__ cand) {
  __shared__ __align__(16) unsigned short As[128 * 72];  // 64 bf16 K + 8 pad
  __shared__ __align__(16) unsigned short Bs[128 * 72];
  const int tid  = threadIdx.x;
  const int wave = tid >> 6;
  const int lane = tid & 63;
  const int quad = lane >> 4;
  const int l16  = lane & 15;
  const int row0 = blockIdx.x * 128;

  float run[2][4];
#pragma unroll
  for (int a = 0; a < 2; ++a)
#pragma unroll
    for (int b = 0; b < 4; ++b) run[a][b] = 1e30f;

  for (int nc = 0; nc < 64; ++nc) {
    const int col0 = nc * 128;
    f32x4 acc[2][8];
#pragma unroll
    for (int a = 0; a < 2; ++a)
#pragma unroll
      for (int b = 0; b < 8; ++b) acc[a][b] = (f32x4){0.f, 0.f, 0.f, 0.f};

    for (int kk = 0; kk < K_DIM; kk += 64) {
      // stage A[128][64] and B[128][64] (bf16): 1024 16B segments total, 4+4 per thread
#pragma unroll
      for (int i = 0; i < 4; ++i) {
        int s = tid + i * 256;
        int r = s >> 3, ks = s & 7;
        int4 va = *(const int4*)(zb + ((size_t)(row0 + r) << 10) + kk + ks * 8);
        *(int4*)(As + r * 72 + ks * 8) = va;
        int4 vb = *(const int4*)(cbTb + ((size_t)(col0 + r) << 10) + kk + ks * 8);
        *(int4*)(Bs + r * 72 + ks * 8) = vb;
      }
      __syncthreads();
#pragma unroll
      for (int ks = 0; ks < 64; ks += 32) {
        bf16x8 a0 = *(const bf16x8*)(As + (wave * 32 + l16) * 72 + ks + quad * 8);
        bf16x8 a1 = *(const bf16x8*)(As + (wave * 32 + 16 + l16) * 72 + ks + quad * 8);
#pragma unroll
        for (int ns = 0; ns < 8; ++ns) {
          bf16x8 b = *(const bf16x8*)(Bs + (ns * 16 + l16) * 72 + ks + quad * 8);
          acc[0][ns] = __builtin_amdgcn_mfma_f32_16x16x32_bf16(a0, b, acc[0][ns], 0, 0, 0);
          acc[1][ns] = __builtin_amdgcn_mfma_f32_16x16x32_bf16(a1, b, acc[1][ns], 0, 0, 0);
        }
      }
      __syncthreads();
    }

    // epilogue: C/D layout row = quad*4 + reg, col = l16 (per 16x16 subtile)
#pragma unroll
    for (int ms = 0; ms < 2; ++ms) {
#pragma unroll
      for (int r = 0; r < 4; ++r) {
        float v = acc[ms][0][r];
#pragma unroll
        for (int ns = 1; ns < 8; ++ns) v = fminf(v, acc[ms][ns][r]);
#pragma unroll
        for (int m = 1; m < 16; m <<= 1) v = fminf(v, __shfl_xor(v, m));
        float rm = fminf(run[ms][r], v);
        run[ms][r] = rm;
        const float thr = rm + MARGIN;
        const int row = row0 + wave * 32 + ms * 16 + quad * 4 + r;
#pragma unroll
        for (int ns = 0; ns < 8; ++ns) {
          if (acc[ms][ns][r] <= thr) {
            int slot = atomicAdd(&counts[row], 1);
            if (slot < CAP) cand[row * CAP + slot] = col0 + ns * 16 + l16;
          }
        }
      }
    }
  }
}

// ---- refine: exact fp64 re-rank of candidates + coalesced gather write ----
__global__ __launch_bounds__(256) void vq_refine(const float* __restrict__ z,
                                                 const float* __restrict__ cbT,
                                                 const int* __restrict__ counts,
                                                 const int* __restrict__ cand,
                                                 float* __restrict__ out) {
  const int row  = blockIdx.x * 4 + (threadIdx.x >> 6);
  const int lane = threadIdx.x & 63;
  const float* zr = z + ((size_t)row << 10);
  const int cnt = counts[row];
  double bestv = 1e300;
  int bestc = 0x7fffffff;
  if (cnt <= CAP) {
    for (int i = 0; i < cnt; ++i) {
      const int c = cand[row * CAP + i];
      const float* cbc = cbT + ((size_t)c << 10);
      double s = 0.0;
#pragma unroll
      for (int j = 0; j < 16; ++j) {
        int k = j * 64 + lane;
        s = fma((double)zr[k], (double)cbc[k], s);
      }
#pragma unroll
      for (int m = 1; m < 64; m <<= 1) s += __shfl_xor(s, m);
      if (s < bestv || (s == bestv && c < bestc)) { bestv = s; bestc = c; }
    }
  } else {
    // overflow fallback: full scan (provably near-never taken)
    for (int c = 0; c < N_COLS; ++c) {
      const float* cbc = cbT + ((size_t)c << 10);
      double s = 0.0;
#pragma unroll
      for (int j = 0; j < 16; ++j) {
        int k = j * 64 + lane;
        s = fma((double)zr[k], (double)cbc[k], s);
      }
#pragma unroll
      for (int m = 1; m < 64; m <<= 1) s += __shfl_xor(s, m);
      if (s < bestv) { bestv = s; bestc = c; }  // ascending c => first-min wins
    }
  }
  if (bestc >= N_COLS || bestc < 0) bestc = 0;  // defensive (cnt>=1 always)
  const float4* src = (const float4*)(cbT + ((size_t)bestc << 10));
  float4* dst = (float4*)(out + ((size_t)row << 10));
#pragma unroll
  for (int j = 0; j < 4; ++j) dst[j * 64 + lane] = src[j * 64 + lane];
}

// ---- safety net if ws is too small: exact fp64 brute force, no workspace ----
__global__ __launch_bounds__(256) void vq_brute(const float* __restrict__ z,
                                                const float* __restrict__ cb,
                                                float* __restrict__ out) {
  const int row = blockIdx.x;
  __shared__ float zr[K_DIM];
  __shared__ double bv[256];
  __shared__ int bc[256];
  for (int i = threadIdx.x; i < K_DIM; i += 256) zr[i] = z[((size_t)row << 10) + i];
  __syncthreads();
  double bestv = 1e300;
  int bestc = 0x7fffffff;
  for (int ci = 0; ci < N_COLS / 256; ++ci) {
    int c = ci * 256 + threadIdx.x;
    double s = 0.0;
    for (int k = 0; k < K_DIM; ++k)
      s = fma((double)zr[k], (double)cb[((size_t)k << 13) + c], s);
    if (s < bestv || (s == bestv && c < bestc)) { bestv = s; bestc = c; }
  }
  bv[threadIdx.x] = bestv; bc[threadIdx.x] = bestc;
  __syncthreads();
  for (int sft = 128; sft > 0; sft >>= 1) {
    if (threadIdx.x < sft) {
      double v2 = bv[threadIdx.x + sft]; int c2 = bc[threadIdx.x + sft];
      if (v2 < bv[threadIdx.x] || (v2 == bv[threadIdx.x] && c2 < bc[threadIdx.x])) {
        bv[threadIdx.x] = v2; bc[threadIdx.x] = c2;
      }
    }
    __syncthreads();
  }
  const int c = bc[0];
  for (int d = threadIdx.x; d < K_DIM; d += 256)
    out[((size_t)row << 10) + d] = cb[((size_t)d << 13) + c];
}

extern "C" void kernel_launch(void* const* d_in, const int* in_sizes, int n_in,
                              void* d_out, int out_size, void* d_ws, size_t ws_size,
                              hipStream_t stream) {
  const float* z  = (const float*)d_in[0];
  const float* cb = (const float*)d_in[1];
  float* out = (float*)d_out;

  const size_t zb_bytes     = (size_t)M_ROWS * K_DIM * 2;  // 128 MB
  const size_t cbT_bytes    = (size_t)N_COLS * K_DIM * 4;  // 32 MB
  const size_t cbTb_bytes   = (size_t)N_COLS * K_DIM * 2;  // 16 MB
  const size_t cand_bytes   = (size_t)M_ROWS * CAP * 4;    // 8 MB
  const size_t counts_bytes = (size_t)M_ROWS * 4;          // 256 KB
  const size_t need = zb_bytes + cbT_bytes + cbTb_bytes + cand_bytes + counts_bytes;

  if (ws_size < need) {
    vq_brute<<<M_ROWS, 256, 0, stream>>>(z, cb, out);
    return;
  }

  char* p = (char*)d_ws;
  unsigned short* zb   = (unsigned short*)p; p += zb_bytes;
  float*          cbT  = (float*)p;          p += cbT_bytes;
  unsigned short* cbTb = (unsigned short*)p; p += cbTb_bytes;
  int*            cand = (int*)p;            p += cand_bytes;
  int*            counts = (int*)p;

  vq_init<<<M_ROWS / 256, 256, 0, stream>>>(counts);
  vq_convert_z<<<(M_ROWS * (K_DIM / 4)) / 256, 256, 0, stream>>>(z, zb);
  vq_transpose_cb<<<dim3(N_COLS / 32, K_DIM / 32), dim3(32, 8), 0, stream>>>(cb, cbT, cbTb);
  vq_gemm<<<M_ROWS / 128, 256, 0, stream>>>(zb, cbTb, counts, cand);
  vq_refine<<<M_ROWS / 4, 256, 0, stream>>>(z, cbT, counts, cand, out);
}

// Round 2
// 2305.524 us; speedup vs baseline: 3.0014x; 3.0014x over previous
//
#include <hip/hip_runtime.h>
#include <hip/hip_bf16.h>

#define M_ROWS 65536
#define N_COLS 8192
#define K_DIM  1024
#define CAP    64
#define MARGIN 1.0f

typedef __attribute__((ext_vector_type(8))) short bf16x8;
typedef __attribute__((ext_vector_type(4))) float f32x4;

__device__ __forceinline__ unsigned short f32_to_bf16_rne(float f) {
  unsigned int u = __float_as_uint(f);
  unsigned int r = u + 0x7fffu + ((u >> 16) & 1u);
  return (unsigned short)(r >> 16);
}

// ---- zero per-row candidate counts (ws is poisoned 0xAA) ----
__global__ void vq_init(int* __restrict__ counts) {
  int i = blockIdx.x * blockDim.x + threadIdx.x;
  if (i < M_ROWS) counts[i] = 0;
}

// ---- z (fp32) -> bf16 ----
__global__ void vq_convert_z(const float* __restrict__ z, unsigned short* __restrict__ zb) {
  int i = blockIdx.x * blockDim.x + threadIdx.x;
  float4 v = ((const float4*)z)[i];
  ushort4 o;
  o.x = f32_to_bf16_rne(v.x);
  o.y = f32_to_bf16_rne(v.y);
  o.z = f32_to_bf16_rne(v.z);
  o.w = f32_to_bf16_rne(v.w);
  ((ushort4*)zb)[i] = o;
}

// ---- transpose codebook [K][N] -> cbT [N][K] fp32 + bf16 ----
__global__ void vq_transpose_cb(const float* __restrict__ cb,
                                float* __restrict__ cbT,
                                unsigned short* __restrict__ cbTb) {
  __shared__ float tile[32][33];
  int n0 = blockIdx.x * 32;
  int k0 = blockIdx.y * 32;
  int tx = threadIdx.x;
  int ty = threadIdx.y;
#pragma unroll
  for (int i = 0; i < 4; ++i) {
    int k = k0 + ty + i * 8;
    tile[ty + i * 8][tx] = cb[(size_t)k * N_COLS + n0 + tx];
  }
  __syncthreads();
#pragma unroll
  for (int i = 0; i < 4; ++i) {
    int n = n0 + ty + i * 8;
    float v = tile[tx][ty + i * 8];
    cbT[(size_t)n * K_DIM + k0 + tx] = v;
    cbTb[(size_t)n * K_DIM + k0 + tx] = f32_to_bf16_rne(v);
  }
}

// ---- fused bf16 MFMA GEMM + per-row running-min + candidate record ----
// grid = M/128; block owns a 128-row stripe, loops over 64 col-chunks of 128.
// Staging: global_load_lds width=16, XOR-swizzled global segment so LDS
// fragment reads (ds_read_b128) spread across all 32 banks (2 lanes/bank).
__global__ __launch_bounds__(256) void vq_gemm(const unsigned short* __restrict__ zb,
                                               const unsigned short* __restrict__ cbTb,
                                               int* __restrict__ counts,
                                               unsigned short* __restrict__ cand) {
  __shared__ __align__(16) unsigned short As[128 * 64];
  __shared__ __align__(16) unsigned short Bs[128 * 64];
  const int tid  = threadIdx.x;
  const int wave = tid >> 6;
  const int lane = tid & 63;
  const int quad = lane >> 4;
  const int l16  = lane & 15;
  const int row0 = blockIdx.x * 128;
  // staging lane roles: row-within-8 = lane>>3, segment = lane&7, swizzled by row&7
  const int rr = lane >> 3;
  const int sgo = (((lane & 7) ^ rr) << 3);  // swizzled k-offset (shorts)
  const int swz = l16 & 7;                   // read-side swizzle key

  float run[2][4];
#pragma unroll
  for (int a = 0; a < 2; ++a)
#pragma unroll
    for (int b = 0; b < 4; ++b) run[a][b] = 1e30f;

  for (int nc = 0; nc < 64; ++nc) {
    const int col0 = nc * 128;
    f32x4 acc[2][8];
#pragma unroll
    for (int a = 0; a < 2; ++a)
#pragma unroll
      for (int b = 0; b < 8; ++b) acc[a][b] = (f32x4){0.f, 0.f, 0.f, 0.f};

    for (int kk = 0; kk < K_DIM; kk += 64) {
      // wave stages rows [wave*32, wave*32+32) of As and Bs: 4 calls x 8 rows each
      const int rbase = wave * 32;
#pragma unroll
      for (int c = 0; c < 4; ++c) {
        const int r = rbase + c * 8;
        const unsigned short* ga = zb + ((size_t)(row0 + r + rr) << 10) + kk + sgo;
        __builtin_amdgcn_global_load_lds(
            (const __attribute__((address_space(1))) void*)ga,
            (__attribute__((address_space(3))) void*)(As + r * 64), 16, 0, 0);
        const unsigned short* gb = cbTb + ((size_t)(col0 + r + rr) << 10) + kk + sgo;
        __builtin_amdgcn_global_load_lds(
            (const __attribute__((address_space(1))) void*)gb,
            (__attribute__((address_space(3))) void*)(Bs + r * 64), 16, 0, 0);
      }
      __syncthreads();
#pragma unroll
      for (int ks = 0; ks < 2; ++ks) {
        const int koff = (((ks * 4 + quad) ^ swz) << 3);
        const int ma0 = wave * 32 + l16;
        bf16x8 a0 = *(const bf16x8*)(As + ma0 * 64 + koff);
        bf16x8 a1 = *(const bf16x8*)(As + (ma0 + 16) * 64 + koff);
#pragma unroll
        for (int ns = 0; ns < 8; ++ns) {
          bf16x8 b = *(const bf16x8*)(Bs + (ns * 16 + l16) * 64 + koff);
          acc[0][ns] = __builtin_amdgcn_mfma_f32_16x16x32_bf16(a0, b, acc[0][ns], 0, 0, 0);
          acc[1][ns] = __builtin_amdgcn_mfma_f32_16x16x32_bf16(a1, b, acc[1][ns], 0, 0, 0);
        }
      }
      __syncthreads();
    }

    // epilogue: C/D layout row = quad*4 + reg, col = l16 (per 16x16 subtile)
#pragma unroll
    for (int ms = 0; ms < 2; ++ms) {
#pragma unroll
      for (int r = 0; r < 4; ++r) {
        float v = acc[ms][0][r];
#pragma unroll
        for (int ns = 1; ns < 8; ++ns) v = fminf(v, acc[ms][ns][r]);
#pragma unroll
        for (int m = 1; m < 16; m <<= 1) v = fminf(v, __shfl_xor(v, m));
        float rm = fminf(run[ms][r], v);
        run[ms][r] = rm;
        const float thr = rm + MARGIN;
        const int row = row0 + wave * 32 + ms * 16 + quad * 4 + r;
#pragma unroll
        for (int ns = 0; ns < 8; ++ns) {
          if (acc[ms][ns][r] <= thr) {
            int slot = atomicAdd(&counts[row], 1);
            if (slot < CAP) cand[(size_t)row * CAP + slot] = (unsigned short)(col0 + ns * 16 + l16);
          }
        }
      }
    }
  }
}

// ---- refine: exact fp64 re-rank of candidates + coalesced gather write ----
__global__ __launch_bounds__(256) void vq_refine(const float* __restrict__ z,
                                                 const float* __restrict__ cbT,
                                                 const int* __restrict__ counts,
                                                 const unsigned short* __restrict__ cand,
                                                 float* __restrict__ out) {
  const int row  = blockIdx.x * 4 + (threadIdx.x >> 6);
  const int lane = threadIdx.x & 63;
  const float* zr = z + ((size_t)row << 10);
  float zk[16];
#pragma unroll
  for (int j = 0; j < 16; ++j) zk[j] = zr[j * 64 + lane];
  const int cnt = counts[row];
  double bestv = 1e300;
  int bestc = 0x7fffffff;
  if (cnt <= CAP) {
    for (int i = 0; i < cnt; ++i) {
      const int c = (int)cand[(size_t)row * CAP + i];
      const float* cbc = cbT + ((size_t)c << 10);
      double s = 0.0;
#pragma unroll
      for (int j = 0; j < 16; ++j)
        s = fma((double)zk[j], (double)cbc[j * 64 + lane], s);
#pragma unroll
      for (int m = 1; m < 64; m <<= 1) s += __shfl_xor(s, m);
      if (s < bestv || (s == bestv && c < bestc)) { bestv = s; bestc = c; }
    }
  } else {
    // overflow fallback: full scan (safety net, probabilistically never taken)
    for (int c = 0; c < N_COLS; ++c) {
      const float* cbc = cbT + ((size_t)c << 10);
      double s = 0.0;
#pragma unroll
      for (int j = 0; j < 16; ++j)
        s = fma((double)zk[j], (double)cbc[j * 64 + lane], s);
#pragma unroll
      for (int m = 1; m < 64; m <<= 1) s += __shfl_xor(s, m);
      if (s < bestv) { bestv = s; bestc = c; }
    }
  }
  if (bestc >= N_COLS || bestc < 0) bestc = 0;  // defensive
  const float4* src = (const float4*)(cbT + ((size_t)bestc << 10));
  float4* dst = (float4*)(out + ((size_t)row << 10));
#pragma unroll
  for (int j = 0; j < 4; ++j) dst[j * 64 + lane] = src[j * 64 + lane];
}

// ---- safety net if ws is too small: exact fp64 brute force, no workspace ----
__global__ __launch_bounds__(256) void vq_brute(const float* __restrict__ z,
                                                const float* __restrict__ cb,
                                                float* __restrict__ out) {
  const int row = blockIdx.x;
  __shared__ float zr[K_DIM];
  __shared__ double bv[256];
  __shared__ int bc[256];
  for (int i = threadIdx.x; i < K_DIM; i += 256) zr[i] = z[((size_t)row << 10) + i];
  __syncthreads();
  double bestv = 1e300;
  int bestc = 0x7fffffff;
  for (int ci = 0; ci < N_COLS / 256; ++ci) {
    int c = ci * 256 + threadIdx.x;
    double s = 0.0;
    for (int k = 0; k < K_DIM; ++k)
      s = fma((double)zr[k], (double)cb[((size_t)k << 13) + c], s);
    if (s < bestv || (s == bestv && c < bestc)) { bestv = s; bestc = c; }
  }
  bv[threadIdx.x] = bestv; bc[threadIdx.x] = bestc;
  __syncthreads();
  for (int sft = 128; sft > 0; sft >>= 1) {
    if (threadIdx.x < sft) {
      double v2 = bv[threadIdx.x + sft]; int c2 = bc[threadIdx.x + sft];
      if (v2 < bv[threadIdx.x] || (v2 == bv[threadIdx.x] && c2 < bc[threadIdx.x])) {
        bv[threadIdx.x] = v2; bc[threadIdx.x] = c2;
      }
    }
    __syncthreads();
  }
  const int c = bc[0];
  for (int d = threadIdx.x; d < K_DIM; d += 256)
    out[((size_t)row << 10) + d] = cb[((size_t)d << 13) + c];
}

extern "C" void kernel_launch(void* const* d_in, const int* in_sizes, int n_in,
                              void* d_out, int out_size, void* d_ws, size_t ws_size,
                              hipStream_t stream) {
  const float* z  = (const float*)d_in[0];
  const float* cb = (const float*)d_in[1];
  float* out = (float*)d_out;

  const size_t zb_bytes     = (size_t)M_ROWS * K_DIM * 2;  // 128 MB
  const size_t cbT_bytes    = (size_t)N_COLS * K_DIM * 4;  // 32 MB
  const size_t cbTb_bytes   = (size_t)N_COLS * K_DIM * 2;  // 16 MB
  const size_t cand_bytes   = (size_t)M_ROWS * CAP * 2;    // 8 MB (u16 indices)
  const size_t counts_bytes = (size_t)M_ROWS * 4;          // 256 KB
  const size_t need = zb_bytes + cbT_bytes + cbTb_bytes + cand_bytes + counts_bytes;

  if (ws_size < need) {
    vq_brute<<<M_ROWS, 256, 0, stream>>>(z, cb, out);
    return;
  }

  char* p = (char*)d_ws;
  unsigned short* zb   = (unsigned short*)p; p += zb_bytes;
  float*          cbT  = (float*)p;          p += cbT_bytes;
  unsigned short* cbTb = (unsigned short*)p; p += cbTb_bytes;
  unsigned short* cand = (unsigned short*)p; p += cand_bytes;
  int*            counts = (int*)p;

  vq_init<<<M_ROWS / 256, 256, 0, stream>>>(counts);
  vq_convert_z<<<(M_ROWS * (K_DIM / 4)) / 256, 256, 0, stream>>>(z, zb);
  vq_transpose_cb<<<dim3(N_COLS / 32, K_DIM / 32), dim3(32, 8), 0, stream>>>(cb, cbT, cbTb);
  vq_gemm<<<M_ROWS / 128, 256, 0, stream>>>(zb, cbTb, counts, cand);
  vq_refine<<<M_ROWS / 4, 256, 0, stream>>>(z, cbT, counts, cand, out);
}